// Round 1
// baseline (151.406 us; speedup 1.0000x reference)
//
#include <hip/hip_runtime.h>

#define B_   32
#define IN_  784
#define HID_ 256
#define OUT_ 128
#define MH_  32
#define RATE_ 1e-3f

// workspace layout (float offsets)
#define OFF_VJ1  0        // [32][256]
#define OFF_OUT1 8192     // [32][256]  (init vj1, accumulated by layer1)
#define OFF_XT   16384    // [784][32]  x transposed
#define OFF_VJ2  41472    // [32][128]
#define OFF_O1T  45568    // [256][32]  out1 transposed
// total 53760 floats = 215 KB

// ---------------- Kernel A: vj1 = relu(x @ W1^T + b1); out1 = vj1; xT = x^T
__global__ void kA(const float* __restrict__ x, const float* __restrict__ W1,
                   const float* __restrict__ b1, float* __restrict__ ws) {
    float* vj1  = ws + OFF_VJ1;
    float* out1 = ws + OFF_OUT1;
    float* xT   = ws + OFF_XT;
    int t = threadIdx.x, blk = blockIdx.x;

    // transpose duty: first 98 blocks cover 25088 elements
    if (blk < 98) {
        int e = blk * 256 + t;          // e = i*32 + b
        int i = e >> 5, b = e & 31;
        xT[e] = x[b * IN_ + i];
    }

    int lane = t & 63;
    int p = blk * 4 + (t >> 6);         // pair index < 8192
    int b = p >> 8, o = p & 255;
    const float* xr = x  + b * IN_;
    const float* wr = W1 + o * IN_;
    float acc = 0.f;
    for (int i = lane; i < IN_; i += 64) acc = fmaf(xr[i], wr[i], acc);
    #pragma unroll
    for (int m = 1; m < 64; m <<= 1) acc += __shfl_xor(acc, m, 64);
    if (lane == 0) {
        float v = fmaxf(acc + b1[o], 0.f);
        vj1[p]  = v;
        out1[p] = v;
    }
}

// ---------------- Layer main: shift = meta(vi, w, vj)*scale;
// Wnew[o,i] = W[o,i] + mean_b shift; outAcc[b,o] += sum_i vi*shift
template<int IN_DIM, int OUT_DIM, int CHUNK>
__global__ void layer_main(const float* __restrict__ viT,   // [IN_DIM][32]
                           const float* __restrict__ W,     // [OUT_DIM][IN_DIM]
                           const float* __restrict__ vj,    // [32][OUT_DIM]
                           const float* __restrict__ mW1, const float* __restrict__ mb1,
                           const float* __restrict__ mW2, const float* __restrict__ mb2,
                           const int*   __restrict__ batch_num,
                           float* __restrict__ Wnew,        // [OUT_DIM][IN_DIM]
                           float* __restrict__ outAcc)      // [32][OUT_DIM]
{
    constexpr int NCH = IN_DIM / CHUNK;
    int t = threadIdx.x;
    int b = t & 31, g = t >> 5;                  // g in [0,8)
    int o  = blockIdx.x / NCH;
    int i0 = (blockIdx.x % NCH) * CHUNK;

    float scale = RATE_ / (float)batch_num[0];
    float vjv = vj[b * OUT_DIM + o];

    float a[MH_], bw[MH_], w2[MH_], pre[MH_];
    #pragma unroll
    for (int h = 0; h < MH_; ++h) {
        a[h]   = mW1[h * 3 + 0];
        bw[h]  = mW1[h * 3 + 1];
        pre[h] = fmaf(mW1[h * 3 + 2], vjv, mb1[h]);
        w2[h]  = mW2[h];
    }
    float mb2v = mb2[0];

    const float* wrow = W + o * IN_DIM;
    float outacc = 0.f;

    #pragma unroll 2
    for (int k = 0; k < CHUNK / 8; ++k) {
        int i = i0 + g + 8 * k;
        float viv = viT[i * 32 + b];             // half-wave coalesced
        float wv  = wrow[i];
        float s0 = 0.f, s1 = 0.f, s2 = 0.f, s3 = 0.f;
        #pragma unroll
        for (int h = 0; h < MH_; h += 4) {
            float t0 = fmaf(a[h+0], viv, fmaf(bw[h+0], wv, pre[h+0])); t0 = fmaxf(t0, 0.f); s0 = fmaf(w2[h+0], t0, s0);
            float t1 = fmaf(a[h+1], viv, fmaf(bw[h+1], wv, pre[h+1])); t1 = fmaxf(t1, 0.f); s1 = fmaf(w2[h+1], t1, s1);
            float t2 = fmaf(a[h+2], viv, fmaf(bw[h+2], wv, pre[h+2])); t2 = fmaxf(t2, 0.f); s2 = fmaf(w2[h+2], t2, s2);
            float t3 = fmaf(a[h+3], viv, fmaf(bw[h+3], wv, pre[h+3])); t3 = fmaxf(t3, 0.f); s3 = fmaf(w2[h+3], t3, s3);
        }
        float shift = (((s0 + s1) + (s2 + s3)) + mb2v) * scale;
        outacc = fmaf(viv, shift, outacc);

        // reduce shift over b (32 lanes within each wave half)
        float r = shift;
        r += __shfl_xor(r, 1);
        r += __shfl_xor(r, 2);
        r += __shfl_xor(r, 4);
        r += __shfl_xor(r, 8);
        r += __shfl_xor(r, 16);
        if (b == 0) Wnew[o * IN_DIM + i] = wrow[i] + r * (1.0f / 32.0f);
    }

    // reduce outacc over g: pair g within wave, then atomics
    outacc += __shfl_xor(outacc, 32);
    if ((t & 32) == 0) atomicAdd(&outAcc[b * OUT_DIM + o], outacc);
}

// ---------------- Kernel C: vj2 = relu(out1 @ W2^T + b2); out2 init; o1T = out1^T
__global__ void kC(const float* __restrict__ out1, const float* __restrict__ W2,
                   const float* __restrict__ b2, float* __restrict__ vj2,
                   float* __restrict__ o1T, float* __restrict__ out2) {
    int t = threadIdx.x, blk = blockIdx.x;

    if (blk < 32) {
        int e = blk * 256 + t;          // e = i*32 + b, e < 8192
        int i = e >> 5, b = e & 31;
        o1T[e] = out1[b * HID_ + i];
    }

    int lane = t & 63;
    int p = blk * 4 + (t >> 6);         // pair < 4096
    int b = p >> 7, o = p & 127;
    const float* xr = out1 + b * HID_;
    const float* wr = W2   + o * HID_;
    float acc = 0.f;
    #pragma unroll
    for (int k = 0; k < 4; ++k) acc = fmaf(xr[lane + 64 * k], wr[lane + 64 * k], acc);
    #pragma unroll
    for (int m = 1; m < 64; m <<= 1) acc += __shfl_xor(acc, m, 64);
    if (lane == 0) {
        float v = fmaxf(acc + b2[o], 0.f);
        vj2[p]  = v;
        out2[p] = v;
    }
}

extern "C" void kernel_launch(void* const* d_in, const int* in_sizes, int n_in,
                              void* d_out, int out_size, void* d_ws, size_t ws_size,
                              hipStream_t stream) {
    const float* x   = (const float*)d_in[0];
    const float* W1  = (const float*)d_in[1];
    const float* b1  = (const float*)d_in[2];
    const float* W2  = (const float*)d_in[3];
    const float* b2  = (const float*)d_in[4];
    const float* mW1 = (const float*)d_in[5];
    const float* mb1 = (const float*)d_in[6];
    const float* mW2 = (const float*)d_in[7];
    const float* mb2 = (const float*)d_in[8];
    const int* batch_num = (const int*)d_in[9];

    float* out2  = (float*)d_out;               // [32*128]
    float* W1n   = out2 + B_ * OUT_;            // [256*784]
    float* W2n   = W1n + HID_ * IN_;            // [128*256]
    float* ws    = (float*)d_ws;

    // A: vj1 + out1 init + xT
    kA<<<2048, 256, 0, stream>>>(x, W1, b1, ws);
    // B: layer 1 main (256 o * 7 chunks of 112)
    layer_main<IN_, HID_, 112><<<HID_ * 7, 256, 0, stream>>>(
        ws + OFF_XT, W1, ws + OFF_VJ1, mW1, mb1, mW2, mb2, batch_num,
        W1n, ws + OFF_OUT1);
    // C: vj2 + out2 init + o1T
    kC<<<1024, 256, 0, stream>>>(ws + OFF_OUT1, W2, b2,
                                 ws + OFF_VJ2, ws + OFF_O1T, out2);
    // D: layer 2 main (128 o * 4 chunks of 64)
    layer_main<HID_, OUT_, 64><<<OUT_ * 4, 256, 0, stream>>>(
        ws + OFF_O1T, W2, ws + OFF_VJ2, mW1, mb1, mW2, mb2, batch_num,
        W2n, out2);
}

// Round 2
// 109.190 us; speedup vs baseline: 1.3866x; 1.3866x over previous
//
#include <hip/hip_runtime.h>

#define B_   32
#define IN_  784
#define HID_ 256
#define OUT_ 128
#define MH_  32
#define RATE_ 1e-3f

// workspace layout (float offsets)
#define OFF_VJ1  0        // [32][256]
#define OFF_OUT1 8192     // [32][256]  (init vj1, accumulated by layer1)
#define OFF_XT   16384    // [784][32]  x transposed
#define OFF_VJ2  41472    // [32][128]
#define OFF_O1T  45568    // [256][32]  out1 transposed

// ---------------- Kernel A: vj1 = relu(x @ W1^T + b1); out1 = vj1; xT = x^T
__global__ void kA(const float* __restrict__ x, const float* __restrict__ W1,
                   const float* __restrict__ b1, float* __restrict__ ws) {
    float* vj1  = ws + OFF_VJ1;
    float* out1 = ws + OFF_OUT1;
    float* xT   = ws + OFF_XT;
    int t = threadIdx.x, blk = blockIdx.x;

    // transpose duty: first 98 blocks cover 25088 elements
    if (blk < 98) {
        int e = blk * 256 + t;          // e = i*32 + b
        int i = e >> 5, b = e & 31;
        xT[e] = x[b * IN_ + i];
    }

    int lane = t & 63;
    int p = blk * 4 + (t >> 6);         // pair index < 8192
    int b = p >> 8, o = p & 255;
    const float4* xr4 = (const float4*)(x  + b * IN_);
    const float4* wr4 = (const float4*)(W1 + o * IN_);
    float acc = 0.f;
    #pragma unroll
    for (int k = 0; k < 3; ++k) {       // 3*64 = 192 float4 = 768 elements
        float4 xa = xr4[lane + 64 * k];
        float4 wa = wr4[lane + 64 * k];
        acc = fmaf(xa.x, wa.x, acc); acc = fmaf(xa.y, wa.y, acc);
        acc = fmaf(xa.z, wa.z, acc); acc = fmaf(xa.w, wa.w, acc);
    }
    if (lane < 4) {                     // tail: float4 192..195 = elements 768..783
        float4 xa = xr4[192 + lane];
        float4 wa = wr4[192 + lane];
        acc = fmaf(xa.x, wa.x, acc); acc = fmaf(xa.y, wa.y, acc);
        acc = fmaf(xa.z, wa.z, acc); acc = fmaf(xa.w, wa.w, acc);
    }
    #pragma unroll
    for (int m = 1; m < 64; m <<= 1) acc += __shfl_xor(acc, m, 64);
    if (lane == 0) {
        float v = fmaxf(acc + b1[o], 0.f);
        vj1[p]  = v;
        out1[p] = v;
    }
}

// ---------------- Layer main ----------------
// shift = meta(vi, w, vj)*scale; Wnew[o,i] = W[o,i] + mean_b shift;
// outAcc[b,o] += sum_i vi*shift
// Thread layout: t = b + 32*g (b = batch lane, g = i-group). Each thread owns
// CPT = CHUNK/8 contiguous i's. Meta params live in LDS (broadcast reads);
// 4 i's processed per h-pass so the 2 LDS reads + pre-fma amortize 4x.

#define PROC4(IBASE)                                                           \
  {                                                                            \
    const int i_ = (IBASE);                                                    \
    float2 wlo = *(const float2*)(wrow + i_);                                  \
    float2 whi = *(const float2*)(wrow + i_ + 2);                              \
    float v0 = viT[(i_+0)*32 + b], v1 = viT[(i_+1)*32 + b];                    \
    float v2 = viT[(i_+2)*32 + b], v3 = viT[(i_+3)*32 + b];                    \
    float s0=0.f, s1=0.f, s2=0.f, s3=0.f;                                      \
    _Pragma("unroll 8")                                                        \
    for (int h = 0; h < MH_; ++h) {                                            \
      float4 m = m4s[h]; float w2 = w2s[h];                                    \
      float pre = fmaf(m.z, vjv, m.w);                                         \
      float t0 = fmaf(m.x, v0, fmaf(m.y, wlo.x, pre)); t0=fmaxf(t0,0.f); s0=fmaf(w2,t0,s0); \
      float t1 = fmaf(m.x, v1, fmaf(m.y, wlo.y, pre)); t1=fmaxf(t1,0.f); s1=fmaf(w2,t1,s1); \
      float t2 = fmaf(m.x, v2, fmaf(m.y, whi.x, pre)); t2=fmaxf(t2,0.f); s2=fmaf(w2,t2,s2); \
      float t3 = fmaf(m.x, v3, fmaf(m.y, whi.y, pre)); t3=fmaxf(t3,0.f); s3=fmaf(w2,t3,s3); \
    }                                                                          \
    float sh0=(s0+mb2v)*scale, sh1=(s1+mb2v)*scale;                            \
    float sh2=(s2+mb2v)*scale, sh3=(s3+mb2v)*scale;                            \
    outacc = fmaf(v0,sh0,fmaf(v1,sh1,fmaf(v2,sh2,fmaf(v3,sh3,outacc))));       \
    float r0=sh0, r1=sh1, r2=sh2, r3=sh3;                                      \
    _Pragma("unroll")                                                          \
    for (int mm = 1; mm < 32; mm <<= 1) {                                      \
      r0 += __shfl_xor(r0, mm); r1 += __shfl_xor(r1, mm);                      \
      r2 += __shfl_xor(r2, mm); r3 += __shfl_xor(r3, mm);                      \
    }                                                                          \
    if (b == 0) {                                                              \
      *(float2*)(wnrow + i_)     = make_float2(wlo.x + r0*0.03125f, wlo.y + r1*0.03125f); \
      *(float2*)(wnrow + i_ + 2) = make_float2(whi.x + r2*0.03125f, whi.y + r3*0.03125f); \
    }                                                                          \
  }

#define PROC2(IBASE)                                                           \
  {                                                                            \
    const int i_ = (IBASE);                                                    \
    float2 wlo = *(const float2*)(wrow + i_);                                  \
    float v0 = viT[(i_+0)*32 + b], v1 = viT[(i_+1)*32 + b];                    \
    float s0=0.f, s1=0.f;                                                      \
    _Pragma("unroll 8")                                                        \
    for (int h = 0; h < MH_; ++h) {                                            \
      float4 m = m4s[h]; float w2 = w2s[h];                                    \
      float pre = fmaf(m.z, vjv, m.w);                                         \
      float t0 = fmaf(m.x, v0, fmaf(m.y, wlo.x, pre)); t0=fmaxf(t0,0.f); s0=fmaf(w2,t0,s0); \
      float t1 = fmaf(m.x, v1, fmaf(m.y, wlo.y, pre)); t1=fmaxf(t1,0.f); s1=fmaf(w2,t1,s1); \
    }                                                                          \
    float sh0=(s0+mb2v)*scale, sh1=(s1+mb2v)*scale;                            \
    outacc = fmaf(v0,sh0,fmaf(v1,sh1,outacc));                                 \
    float r0=sh0, r1=sh1;                                                      \
    _Pragma("unroll")                                                          \
    for (int mm = 1; mm < 32; mm <<= 1) {                                      \
      r0 += __shfl_xor(r0, mm); r1 += __shfl_xor(r1, mm);                      \
    }                                                                          \
    if (b == 0) {                                                              \
      *(float2*)(wnrow + i_) = make_float2(wlo.x + r0*0.03125f, wlo.y + r1*0.03125f); \
    }                                                                          \
  }

template<int IN_DIM, int OUT_DIM, int CHUNK>
__global__ __launch_bounds__(256)
void layer_main(const float* __restrict__ viT,   // [IN_DIM][32]
                const float* __restrict__ W,     // [OUT_DIM][IN_DIM]
                const float* __restrict__ vj,    // [32][OUT_DIM]
                const float* __restrict__ mW1, const float* __restrict__ mb1,
                const float* __restrict__ mW2, const float* __restrict__ mb2,
                const int*   __restrict__ batch_num,
                float* __restrict__ Wnew,        // [OUT_DIM][IN_DIM]
                float* __restrict__ outAcc)      // [32][OUT_DIM]
{
    constexpr int NCH = IN_DIM / CHUNK;
    constexpr int CPT = CHUNK / 8;               // contiguous i's per thread
    __shared__ float4 m4s[MH_];                  // {a, bw, c, mb1}
    __shared__ float  w2s[MH_];
    __shared__ float  osh[4][32];

    int t = threadIdx.x;
    int b = t & 31, g = t >> 5;
    int o  = blockIdx.x / NCH;
    int i0 = (blockIdx.x % NCH) * CHUNK + g * CPT;

    if (t < MH_) {
        m4s[t] = make_float4(mW1[t*3+0], mW1[t*3+1], mW1[t*3+2], mb1[t]);
        w2s[t] = mW2[t];
    }
    __syncthreads();

    float scale = RATE_ / (float)batch_num[0];
    float vjv   = vj[b * OUT_DIM + o];
    float mb2v  = mb2[0];
    const float* wrow  = W    + o * IN_DIM;
    float*       wnrow = Wnew + o * IN_DIM;
    float outacc = 0.f;

    for (int c = 0; c + 4 <= CPT; c += 4) PROC4(i0 + c);
    if (CPT & 2) PROC2(i0 + (CPT & ~3));

    // reduce outacc over g: pair waves' halves, stage per-wave partials in LDS
    outacc += __shfl_xor(outacc, 32);
    if ((t & 32) == 0) osh[t >> 6][b] = outacc;
    __syncthreads();
    if (t < 32) {
        float v = osh[0][t] + osh[1][t] + osh[2][t] + osh[3][t];
        atomicAdd(&outAcc[t * OUT_DIM + o], v);
    }
}

// ---------------- Kernel C: vj2 = relu(out1 @ W2^T + b2); out2 init; o1T = out1^T
__global__ void kC(const float* __restrict__ out1, const float* __restrict__ W2,
                   const float* __restrict__ b2, float* __restrict__ vj2,
                   float* __restrict__ o1T, float* __restrict__ out2) {
    int t = threadIdx.x, blk = blockIdx.x;

    if (blk < 32) {
        int e = blk * 256 + t;          // e = i*32 + b, e < 8192
        int i = e >> 5, b = e & 31;
        o1T[e] = out1[b * HID_ + i];
    }

    int lane = t & 63;
    int p = blk * 4 + (t >> 6);         // pair < 4096
    int b = p >> 7, o = p & 127;
    const float4* xr4 = (const float4*)(out1 + b * HID_);
    const float4* wr4 = (const float4*)(W2   + o * HID_);
    float4 xa = xr4[lane];              // 64 lanes * 4 = 256 elements exactly
    float4 wa = wr4[lane];
    float acc = fmaf(xa.x, wa.x, fmaf(xa.y, wa.y, fmaf(xa.z, wa.z, xa.w * wa.w)));
    #pragma unroll
    for (int m = 1; m < 64; m <<= 1) acc += __shfl_xor(acc, m, 64);
    if (lane == 0) {
        float v = fmaxf(acc + b2[o], 0.f);
        vj2[p]  = v;
        out2[p] = v;
    }
}

extern "C" void kernel_launch(void* const* d_in, const int* in_sizes, int n_in,
                              void* d_out, int out_size, void* d_ws, size_t ws_size,
                              hipStream_t stream) {
    const float* x   = (const float*)d_in[0];
    const float* W1  = (const float*)d_in[1];
    const float* b1  = (const float*)d_in[2];
    const float* W2  = (const float*)d_in[3];
    const float* b2  = (const float*)d_in[4];
    const float* mW1 = (const float*)d_in[5];
    const float* mb1 = (const float*)d_in[6];
    const float* mW2 = (const float*)d_in[7];
    const float* mb2 = (const float*)d_in[8];
    const int* batch_num = (const int*)d_in[9];

    float* out2  = (float*)d_out;               // [32*128]
    float* W1n   = out2 + B_ * OUT_;            // [256*784]
    float* W2n   = W1n + HID_ * IN_;            // [128*256]
    float* ws    = (float*)d_ws;

    // A: vj1 + out1 init + xT
    kA<<<2048, 256, 0, stream>>>(x, W1, b1, ws);
    // B: layer 1 main (256 o * 7 chunks of 112; CPT = 14 -> 3xPROC4 + PROC2)
    layer_main<IN_, HID_, 112><<<HID_ * 7, 256, 0, stream>>>(
        ws + OFF_XT, W1, ws + OFF_VJ1, mW1, mb1, mW2, mb2, batch_num,
        W1n, ws + OFF_OUT1);
    // C: vj2 + out2 init + o1T
    kC<<<1024, 256, 0, stream>>>(ws + OFF_OUT1, W2, b2,
                                 ws + OFF_VJ2, ws + OFF_O1T, out2);
    // D: layer 2 main (128 o * 8 chunks of 32; CPT = 4 -> 1xPROC4)
    layer_main<HID_, OUT_, 32><<<OUT_ * 8, 256, 0, stream>>>(
        ws + OFF_O1T, W2, ws + OFF_VJ2, mW1, mb1, mW2, mb2, batch_num,
        W2n, out2);
}